// Round 6
// baseline (231.307 us; speedup 1.0000x reference)
//
#include <hip/hip_runtime.h>

#define CELLS 81
#define ND 9
#define HID 100

__global__ __launch_bounds__(64) void sudoku_kernel(
    const float* __restrict__ x_all,
    const float* __restrict__ W1,
    const float* __restrict__ W2,
    float* __restrict__ out,
    int nBoards)
{
    const int board = blockIdx.x;
    const int l = threadIdx.x;              // one wave per board, lockstep
    const float* x = x_all + (size_t)board * (CELLS * ND);
    float* po = out + (size_t)board * (CELLS * ND);
    float* fo = out + (size_t)nBoards * (CELLS * ND) + (size_t)board * (CELLS * ND);

    __shared__ __align__(16) float w1s[HID * 27];   // 10800 B (init staging)
    __shared__ __align__(16) float zbuf[64 * HID];  // 25600 B (init staging)
    __shared__ float cnt[3 * 81];
    __shared__ int   digit[CELLS];
    __shared__ int   lstq[64];

    // ---- init: stage W1, zero cnt, copy x -> po ----
    for (int i = l; i < (HID * 27) / 4; i += 64)
        ((float4*)w1s)[i] = ((const float4*)W1)[i];
    for (int i = l; i < 243; i += 64) cnt[i] = 0.f;
    for (int i = l; i < CELLS * ND; i += 64) po[i] = x[i];

    // ---- digits, counts, emptiness masks ----
    unsigned long long em0, em1;
    {
        int q = l, dig = -1;
        #pragma unroll
        for (int d = 0; d < ND; ++d) if (dig < 0 && x[q * ND + d] > 0.5f) dig = d;
        digit[q] = dig;
        if (dig >= 0) {
            int r = q / 9, c = q % 9, b = (r / 3) * 3 + c / 3;
            atomicAdd(&cnt[r * 9 + dig], 1.f);
            atomicAdd(&cnt[81 + c * 9 + dig], 1.f);
            atomicAdd(&cnt[162 + b * 9 + dig], 1.f);
        }
        em0 = __ballot(dig < 0);
    }
    {
        bool vv = l < (CELLS - 64);
        int q = 64 + l, dig = 0;
        if (vv) {
            dig = -1;
            #pragma unroll
            for (int d = 0; d < ND; ++d) if (dig < 0 && x[q * ND + d] > 0.5f) dig = d;
            digit[q] = dig;
            if (dig >= 0) {
                int r = q / 9, c = q % 9, b = (r / 3) * 3 + c / 3;
                atomicAdd(&cnt[r * 9 + dig], 1.f);
                atomicAdd(&cnt[81 + c * 9 + dig], 1.f);
                atomicAdd(&cnt[162 + b * 9 + dig], 1.f);
            }
        }
        em1 = __ballot(vv && dig < 0);
    }
    const int c0  = __popcll(em0);
    const int ne0 = c0 + __popcll(em1);

    // lane l -> rank-l empty cell (sentinel 127 = no cell)
    int myq = 127;
    if (l < ne0) {
        int rank = l; unsigned long long mm = em0; int base = 0;
        if (rank >= c0) { rank -= c0; mm = em1; base = 64; }
        for (int b = 0; b < 64; ++b)
            if ((mm >> b) & 1ull) { if (rank == 0) { myq = base + b; break; } --rank; }
    }
    lstq[l] = myq;

    // ---- z init staged through LDS (shared work), then into registers ----
    for (int i = l; i < ne0 * HID; i += 64) {
        int slot = i / HID, u = i - slot * HID;
        int q = lstq[slot];
        int r = q / 9, c = q % 9, b = (r / 3) * 3 + c / 3;
        const float* w = &w1s[u * 27];
        float a = 0.f;
        #pragma unroll
        for (int j = 0; j < 9; ++j)
            a += cnt[r * 9 + j] * w[j] + cnt[81 + c * 9 + j] * w[9 + j]
               + cnt[162 + b * 9 + j] * w[18 + j];
        zbuf[slot * HID + u] = a;
    }

    float z[HID];
    #pragma unroll
    for (int u = 0; u < HID; u += 4) {
        float4 t = *(const float4*)&zbuf[l * HID + u];
        z[u] = t.x; z[u + 1] = t.y; z[u + 2] = t.z; z[u + 3] = t.w;
    }

    const int myr = myq / 9, myc = myq % 9, myb = (myr / 3) * 3 + myc / 3;
    bool active = (l < ne0);
    float smax[ND];
    float scoreV = -1.f; int scoreD = 0;
    float b0 = 0.f, b1 = 0.f, b2 = 0.f;   // this-iteration z-delta coefficients
    int dc = 0;

    // ---- solve loop: one placement per iteration, ne0 iterations ----
    for (int it = 0; it < ne0; ++it) {
        const int dcs = __builtin_amdgcn_readfirstlane(dc);
        const float* __restrict__ w1c = W1 + dcs;   // uniform -> s_load

        float acc[ND];
        #pragma unroll
        for (int d = 0; d < ND; ++d) acc[d] = 0.f;

        // fused z-update + hidden relu + output logits (all weights uniform)
        #pragma unroll
        for (int u = 0; u < HID; ++u) {
            float A = w1c[u * 27], Bv = w1c[u * 27 + 9], Cv = w1c[u * 27 + 18];
            z[u] = b0 * A + (b1 * Bv + (b2 * Cv + z[u]));   // 3 fma
            float h = fmaxf(z[u], 0.f);
            #pragma unroll
            for (int d = 0; d < ND; ++d) acc[d] += h * W2[d * HID + u];
        }

        // softmax + per-cell best digit (first-max semantics)
        float m9 = acc[0];
        #pragma unroll
        for (int d = 1; d < ND; ++d) m9 = fmaxf(m9, acc[d]);
        float s = 0.f;
        #pragma unroll
        for (int d = 0; d < ND; ++d) { acc[d] = expf(acc[d] - m9); s += acc[d]; }
        float inv = 1.f / s;
        float bv = -1.f; int bd = 0;
        #pragma unroll
        for (int d = 0; d < ND; ++d) {
            acc[d] *= inv;
            if (acc[d] > bv) { bv = acc[d]; bd = d; }   // strict >: first max
        }
        if (active) {
            #pragma unroll
            for (int d = 0; d < ND; ++d) smax[d] = acc[d];
            scoreV = bv; scoreD = bd;
        }

        // global argmax: packed u64 key, 6-round butterfly.
        // key = scoreV bits (positive float, int-monotone) | (127-q) | d
        // -> max value, tie -> smallest q (jnp.argmax first occurrence)
        unsigned long long key = 0ull;
        if (active)
            key = ((unsigned long long)__float_as_uint(scoreV) << 32)
                | (unsigned)(((127 - myq) << 4) | scoreD);
        #pragma unroll
        for (int off = 32; off >= 1; off >>= 1) {
            unsigned long long o = __shfl_xor(key, off);
            if (o > key) key = o;
        }
        const int qw = 127 - ((int)(key >> 4) & 0x7F);
        const int dw = (int)(key & 0xFull);

        // place: winner lane writes its final softmax to po, retires
        if (active && myq == qw) {
            #pragma unroll
            for (int d = 0; d < ND; ++d) po[myq * ND + d] = smax[d];
            digit[myq] = dw;
            active = false;
            scoreV = -1.f;
        }

        // delta coefficients for next iteration's z update
        const int pr = qw / 9, pcc = qw % 9, pb = (pr / 3) * 3 + pcc / 3;
        b0 = (myr == pr)  ? 1.f : 0.f;
        b1 = (myc == pcc) ? 1.f : 0.f;
        b2 = (myb == pb)  ? 1.f : 0.f;
        dc = dw;
    }

    // ---- x_final ----
    for (int i = l; i < CELLS * ND; i += 64) {
        int q = i / ND, d = i - q * ND;
        fo[i] = (digit[q] == d) ? 1.f : 0.f;
    }
}

extern "C" void kernel_launch(void* const* d_in, const int* in_sizes, int n_in,
                              void* d_out, int out_size, void* d_ws, size_t ws_size,
                              hipStream_t stream) {
    const float* x  = (const float*)d_in[0];
    // d_in[1] is the constraint mask c — structurally known, not needed.
    const float* W1 = (const float*)d_in[2];
    const float* W2 = (const float*)d_in[3];
    float* out = (float*)d_out;
    int nBoards = in_sizes[0] / (CELLS * ND);
    sudoku_kernel<<<nBoards, 64, 0, stream>>>(x, W1, W2, out, nBoards);
}

// Round 7
// 174.470 us; speedup vs baseline: 1.3258x; 1.3258x over previous
//
#include <hip/hip_runtime.h>

#define CELLS 81
#define ND 9
#define HID 100
#define HALF 50

__global__ __launch_bounds__(128) void sudoku_kernel(
    const float* __restrict__ x_all,
    const float* __restrict__ W1,
    const float* __restrict__ W2,
    float* __restrict__ out,
    int nBoards)
{
    const int board = blockIdx.x;
    const int tid = threadIdx.x;      // 0..127, two waves per board
    const int w   = tid >> 6;         // wave id: owns units [w*50, w*50+50)
    const int lw  = tid & 63;         // lane within wave = empty-cell slot
    const int ubase = w * HALF;

    const float* x = x_all + (size_t)board * (CELLS * ND);
    float* po = out + (size_t)board * (CELLS * ND);
    float* fo = out + (size_t)nBoards * (CELLS * ND) + (size_t)board * (CELLS * ND);

    __shared__ float w1s[HID * 27];                    // 10800 B
    __shared__ __align__(16) float w2t[HID * 12];      // 4800 B, [u][d] pad 12
    __shared__ float parts[2 * 2 * 64 * 10];           // 10240 B dbuf partials
    __shared__ float cnt[3 * 81];
    __shared__ int   digit[CELLS];
    __shared__ unsigned long long em_sh[2];

    // ---- stage weights, zero counts, copy x -> po ----
    for (int i = tid; i < HID * 27; i += 128) w1s[i] = W1[i];
    for (int i = tid; i < HID * ND; i += 128) {
        int d = i / HID, u = i - d * HID;
        w2t[u * 12 + d] = W2[i];
    }
    for (int i = tid; i < 243; i += 128) cnt[i] = 0.f;
    for (int i = tid; i < CELLS * ND; i += 128) po[i] = x[i];
    __syncthreads();

    // ---- digits, counts, per-wave emptiness ballots ----
    bool isEmpty = false;
    if (tid < CELLS) {
        int q = tid, dig = -1;
        #pragma unroll
        for (int d = 0; d < ND; ++d) if (dig < 0 && x[q*ND+d] > 0.5f) dig = d;
        digit[q] = dig;
        if (dig >= 0) {
            int r = q/9, c = q%9, b = (r/3)*3 + c/3;
            atomicAdd(&cnt[r*9+dig], 1.f);
            atomicAdd(&cnt[81+c*9+dig], 1.f);
            atomicAdd(&cnt[162+b*9+dig], 1.f);
        } else isEmpty = true;
    }
    unsigned long long mk = __ballot(isEmpty);   // per-wave 64-bit mask
    if (lw == 0) em_sh[w] = mk;
    __syncthreads();   // counts + masks + digit visible

    const unsigned long long em0 = em_sh[0], em1 = em_sh[1];
    const int c0  = __popcll(em0);
    const int ne0 = c0 + __popcll(em1);

    // lane lw -> rank-lw empty cell (sentinel 127); identical in both waves
    int myq = 127;
    if (lw < ne0) {
        int rank = lw; unsigned long long mm = em0; int base = 0;
        if (rank >= c0) { rank -= c0; mm = em1; base = 64; }
        for (int b = 0; b < 64; ++b)
            if ((mm >> b) & 1ull) { if (rank == 0) { myq = base + b; break; } --rank; }
    }
    const int myr = (myq < 81) ? myq / 9 : 0;
    const int myc = (myq < 81) ? myq % 9 : 0;
    const int myb = (myr / 3) * 3 + myc / 3;

    // ---- z init: my cell's 27 counts in regs, 50 own units ----
    float crr[9], ccc[9], cbb[9];
    #pragma unroll
    for (int j = 0; j < 9; ++j) {
        crr[j] = cnt[myr*9+j];
        ccc[j] = cnt[81+myc*9+j];
        cbb[j] = cnt[162+myb*9+j];
    }
    float z[HALF];
    #pragma unroll
    for (int u = 0; u < HALF; ++u) {
        const float* wr = &w1s[(ubase+u)*27];
        float a = 0.f;
        #pragma unroll
        for (int j = 0; j < 9; ++j)
            a += crr[j]*wr[j] + ccc[j]*wr[9+j] + cbb[j]*wr[18+j];
        z[u] = a;
    }

    bool active = (lw < ne0);
    float b0 = 0.f, b1 = 0.f, b2 = 0.f;   // this-iter z-delta coefficients
    int dc = 0;

    // ---- solve loop: 1 barrier/iter (double-buffered partials) ----
    for (int it = 0; it < ne0; ++it) {
        const int dcs = __builtin_amdgcn_readfirstlane(dc);
        const float* w1p = &w1s[ubase*27 + dcs];   // uniform LDS broadcast
        const float* w2p = &w2t[ubase*12];

        float acc[ND];
        #pragma unroll
        for (int d = 0; d < ND; ++d) acc[d] = 0.f;

        // fused z-update + relu + partial logits over own 50 units
        #pragma unroll
        for (int u = 0; u < HALF; ++u) {
            float A = w1p[u*27], B = w1p[u*27+9], C = w1p[u*27+18];
            z[u] = fmaf(b0, A, fmaf(b1, B, fmaf(b2, C, z[u])));
            float h = fmaxf(z[u], 0.f);
            float4 wa = *(const float4*)&w2p[u*12];
            float4 wb = *(const float4*)&w2p[u*12 + 4];
            float  wc = w2p[u*12 + 8];
            acc[0] += h*wa.x; acc[1] += h*wa.y; acc[2] += h*wa.z; acc[3] += h*wa.w;
            acc[4] += h*wb.x; acc[5] += h*wb.y; acc[6] += h*wb.z; acc[7] += h*wb.w;
            acc[8] += h*wc;
        }

        // publish partial, combine with other wave's half
        const int buf = it & 1;
        float* pp = &parts[((buf*2 + w)*64 + lw)*10];
        #pragma unroll
        for (int d = 0; d < ND; ++d) pp[d] = acc[d];
        __syncthreads();
        const float* op = &parts[((buf*2 + (1-w))*64 + lw)*10];
        #pragma unroll
        for (int d = 0; d < ND; ++d) acc[d] += op[d];   // own+other: commutative
                                                        // -> identical in both waves
        // softmax + per-cell best digit (strict >: first max)
        float m9 = acc[0];
        #pragma unroll
        for (int d = 1; d < ND; ++d) m9 = fmaxf(m9, acc[d]);
        float s = 0.f;
        #pragma unroll
        for (int d = 0; d < ND; ++d) { acc[d] = expf(acc[d] - m9); s += acc[d]; }
        float inv = 1.f / s;
        float bv = -1.f; int bd = 0;
        #pragma unroll
        for (int d = 0; d < ND; ++d) {
            acc[d] *= inv;
            if (acc[d] > bv) { bv = acc[d]; bd = d; }
        }

        // global argmax: packed key -> max value, tie -> smallest q, first digit
        unsigned long long key = 0ull;
        if (active)
            key = ((unsigned long long)__float_as_uint(bv) << 32)
                | (unsigned)(((127 - myq) << 4) | bd);
        #pragma unroll
        for (int off = 32; off >= 1; off >>= 1) {
            unsigned long long o = __shfl_xor(key, off);
            if (o > key) key = o;
        }
        const int qw = 127 - ((int)(key >> 4) & 0x7F);
        const int dw = (int)(key & 0xFull);

        // winner retires: wave 0's copy writes po (final softmax) + digit
        if (active && myq == qw) {
            if (w == 0) {
                #pragma unroll
                for (int d = 0; d < ND; ++d) po[myq*ND + d] = acc[d];
                digit[myq] = dw;
            }
            active = false;
        }
        const int pr = qw/9, pcc = qw%9, pb = (pr/3)*3 + pcc/3;
        b0 = (myr == pr)  ? 1.f : 0.f;
        b1 = (myc == pcc) ? 1.f : 0.f;
        b2 = (myb == pb)  ? 1.f : 0.f;
        dc = dw;
    }

    // ---- x_final ----
    __syncthreads();
    for (int i = tid; i < CELLS * ND; i += 128) {
        int q = i / ND, d = i - q * ND;
        fo[i] = (digit[q] == d) ? 1.f : 0.f;
    }
}

extern "C" void kernel_launch(void* const* d_in, const int* in_sizes, int n_in,
                              void* d_out, int out_size, void* d_ws, size_t ws_size,
                              hipStream_t stream) {
    const float* x  = (const float*)d_in[0];
    // d_in[1] is the constraint mask c — structurally known, not needed.
    const float* W1 = (const float*)d_in[2];
    const float* W2 = (const float*)d_in[3];
    float* out = (float*)d_out;
    int nBoards = in_sizes[0] / (CELLS * ND);
    sudoku_kernel<<<nBoards, 128, 0, stream>>>(x, W1, W2, out, nBoards);
}